// Round 5
// baseline (774.202 us; speedup 1.0000x reference)
//
#include <hip/hip_runtime.h>
#include <math.h>
#include <stdint.h>

#define NDIM 128
#define B_GRAPHS 8192
#define IDX 16
#define EPG 32
#define NN (B_GRAPHS*IDX)      // 131072 nodes
#define NE (B_GRAPHS*EPG)      // 262144 edges

typedef short bf16x8 __attribute__((ext_vector_type(8)));
typedef float f32x4  __attribute__((ext_vector_type(4)));

__device__ inline unsigned short f2bf(float x) {
    union { float f; unsigned u; } v; v.f = x;
    unsigned r = v.u + 0x7fff + ((v.u >> 16) & 1);
    return (unsigned short)(r >> 16);
}
__device__ inline float bf2f(unsigned short b) {
    union { unsigned u; float f; } v; v.u = ((unsigned)b) << 16;
    return v.f;
}
__device__ inline float sigm(float x) { return 1.f/(1.f + __expf(-x)); }
__device__ inline float tanh_f(float x) {
    float ax = fabsf(x);
    float t  = __expf(-2.f*ax);
    float r  = (1.f - t)/(1.f + t);
    return copysignf(r, x);
}

// ---------------------------------------------------------------------------
// Compose bf16 weight matrix WB[l][col'][k] (512 cols x 640 K) and c34.
// K segments: [S_in(128)|S_out(128)|indeg*h(128)|outdeg*h(128)|h(128)]
// Column interleave: col' = (c>>5)*128 + type*32 + (c&31), type in {r,z,gin,ghn}
// so each 128-col' quarter holds all 4 output types for 32 channels.
// ---------------------------------------------------------------------------
__global__ __launch_bounds__(256) void compose_kernel(
    const float* __restrict__ msg_W, const float* __restrict__ msgr_W,
    const float* __restrict__ Wih,   const float* __restrict__ Whh,
    const float* __restrict__ msg_b, const float* __restrict__ msgr_b,
    unsigned short* __restrict__ WB, float* __restrict__ c34)
{
    int idx = blockIdx.x*256 + threadIdx.x;
    const int TWB = 2*512*640;
    if (idx < TWB) {
        int l = idx / (512*640); int rem = idx - l*(512*640);
        int cold = rem / 640; int k = rem - cold*640;
        float val;
        if (k < 512) {
            if (cold < 384) {
                const float* wih = Wih + l*384*256 + cold*256;
                const float* M; int sc;
                if (k < 128)      { M = msg_W  + l*256*256; sc = k;       }
                else if (k < 256) { M = msgr_W + l*256*256; sc = k - 128; }
                else if (k < 384) { M = msg_W  + l*256*256; sc = k - 128; }
                else              { M = msgr_W + l*256*256; sc = k - 256; }
                float acc = 0.f;
                for (int q = 0; q < 256; q++) acc = fmaf(wih[q], M[q*256 + sc], acc);
                val = acc;
            } else val = 0.f;
        } else {
            int kk = k - 512;
            if (cold < 256)      val = Whh[l*384*128 + cold*128 + kk];
            else if (cold < 384) val = 0.f;
            else                 val = Whh[l*384*128 + (cold-128)*128 + kk];
        }
        int cc = cold & 127, t = cold >> 7;
        int colp = ((cc >> 5) << 7) + (t << 5) + (cc & 31);
        WB[l*512*640 + colp*640 + k] = f2bf(val);
    } else if (idx < TWB + 2*2*384) {
        int i2 = idx - TWB;
        int l = i2 / 768; int rem = i2 - l*768;
        int which = rem / 384; int r = rem - which*384;
        const float* wih = Wih + l*384*256 + r*256;
        const float* bb  = (which ? msgr_b : msg_b) + l*256;
        float acc = 0.f;
        for (int q = 0; q < 256; q++) acc = fmaf(wih[q], bb[q], acc);
        c34[l*768 + which*384 + r] = acc;
    }
}

// ---------------------------------------------------------------------------
// Mega kernel: per block = 8 graphs (128 rows). Everything in LDS:
//   S  [128][256] bf16 swizzled  (64 KB)
//   h  [128][128] bf16 swizzled  (32 KB)
// GEMM: 8 waves = 2 row-halves x 4 col-quarters; B-frags direct global->VGPR
// (WB L2-resident); di*h/do*h K-segments generated by per-lane frag scaling.
// GRU combines r/z/gin/ghn entirely in registers (column interleave).
// Scatter via per-graph CSR gather (built once at init). Pool fused at end.
// ---------------------------------------------------------------------------
struct MegaSmem {
    unsigned short S[128*256];    // byte: row*512 + (((e>>3)^(row&7))<<4) + (e&7)*2
    unsigned short hreg[128*128]; // byte: row*256 + (((c>>3)^(row&7))<<4) + (c&7)*2
    unsigned char sl8[256], dl8[256];
    unsigned char csr[8][2][17];
    unsigned char adj[8][2][32];
    unsigned char off[8][2][16];
    float degf[128][2];
    float gates[2][128];
    int flag64;
};

__device__ __forceinline__ int s_addr(int row, int e) {
    return row*512 + (((e>>3) ^ (row&7))<<4) + ((e&7)<<1);
}
__device__ __forceinline__ int h_addr(int row, int c) {
    return row*256 + (((c>>3) ^ (row&7))<<4) + ((c&7)<<1);
}

// gather S from hreg via CSR (used for initial S and layer-0 scatter)
__device__ __forceinline__ void gatherS(MegaSmem& sm, int tid) {
    int c = tid & 127, gq = tid >> 7;
    for (int gi2 = 0; gi2 < 2; gi2++) {
        int gl = gq + gi2*4, rb = gl*16;
        for (int d = 0; d < 16; d++) {
            float a = 0.f;
            int s0 = sm.csr[gl][0][d], s1 = sm.csr[gl][0][d+1];
            for (int j = s0; j < s1; j++)
                a += bf2f(*(const unsigned short*)((const char*)sm.hreg
                        + h_addr(rb + sm.adj[gl][0][j], c)));
            *(unsigned short*)((char*)sm.S + s_addr(rb + d, c)) = f2bf(a);
            float b = 0.f;
            s0 = sm.csr[gl][1][d]; s1 = sm.csr[gl][1][d+1];
            for (int j = s0; j < s1; j++)
                b += bf2f(*(const unsigned short*)((const char*)sm.hreg
                        + h_addr(rb + sm.adj[gl][1][j], c)));
            *(unsigned short*)((char*)sm.S + s_addr(rb + d, 128 + c)) = f2bf(b);
        }
    }
}

#define MF(a,b,c) __builtin_amdgcn_mfma_f32_16x16x32_bf16((a),(b),(c),0,0,0)
#define LB(t,cct,kt) (*(const bf16x8*)(WBl + (size_t)(ch*128 + (t)*32 + (cct)*16 + l15)*640 + (kt)*32 + l4*8))

__global__ __launch_bounds__(512, 2) void mega_kernel(
    const float* __restrict__ hin, const int* __restrict__ ei,
    const unsigned short* __restrict__ WB, const float* __restrict__ c34,
    const float* __restrict__ bih, const float* __restrict__ bhh,
    const float* __restrict__ gmW,  const float* __restrict__ gmb,
    const float* __restrict__ gmiW, const float* __restrict__ gmib,
    float* __restrict__ hf, float* __restrict__ P1, float* __restrict__ P2,
    float* __restrict__ sg)
{
    __shared__ MegaSmem sm;
    const int n0  = blockIdx.x * 128;
    const int g0  = blockIdx.x * 8;
    const int tid = threadIdx.x;
    const int lane = tid & 63, wid = tid >> 6;
    const int rh = wid >> 2, ch = wid & 3;
    const int l15 = lane & 15, l4 = lane >> 4;
    const int rowb = rh * 64;

    // ---------- init: h -> LDS (bf16 swizzled) ----------
    if (tid == 0) {
        int orv = 0;
        for (int i = 1; i < 64; i += 2) orv |= ei[i];
        sm.flag64 = (orv == 0);
    }
    for (int i = 0; i < 32; i++) {
        int idx = i*512 + tid; int row = idx >> 7, c = idx & 127;
        float v = hin[(size_t)(n0 + row)*128 + c];
        *(unsigned short*)((char*)sm.hreg + h_addr(row, c)) = f2bf(v);
    }
    __syncthreads();
    // ---------- edge decode ----------
    if (tid < 256) {
        int gl = tid >> 5;
        int e = (g0 + gl)*32 + (tid & 31);
        int sv, dv;
        if (sm.flag64) { sv = ei[2*e]; dv = ei[2*(NE + e)]; }
        else           { sv = ei[e];   dv = ei[NE + e];     }
        sm.sl8[tid] = (unsigned char)(sv - (g0 + gl)*16);
        sm.dl8[tid] = (unsigned char)(dv - (g0 + gl)*16);
    }
    __syncthreads();
    // ---------- CSR build (counting sort), threads 0..15 ----------
    if (tid < 16) {
        int gl = tid >> 1, dir = tid & 1;
        const unsigned char* key = dir ? sm.sl8 : sm.dl8;
        const unsigned char* val = dir ? sm.dl8 : sm.sl8;
        unsigned char* C = sm.csr[gl][dir];
        for (int d = 0; d < 17; d++) C[d] = 0;
        for (int e2 = 0; e2 < 32; e2++) C[key[gl*32 + e2] + 1]++;
        for (int d = 0; d < 16; d++) { C[d+1] += C[d]; sm.off[gl][dir][d] = C[d]; }
        for (int e2 = 0; e2 < 32; e2++) {
            int k = key[gl*32 + e2];
            sm.adj[gl][dir][sm.off[gl][dir][k]++] = val[gl*32 + e2];
        }
    }
    __syncthreads();
    if (tid < 128) {
        int gl = tid >> 4, d = tid & 15;
        sm.degf[tid][0] = (float)(sm.csr[gl][0][d+1] - sm.csr[gl][0][d]);
        sm.degf[tid][1] = (float)(sm.csr[gl][1][d+1] - sm.csr[gl][1][d]);
    }
    __syncthreads();
    gatherS(sm, tid);
    __syncthreads();

    // ---------- two GNN layers ----------
    for (int l = 0; l < 2; l++) {
        const unsigned short* WBl = WB + (size_t)l*512*640;
        const float* c34l = c34 + l*768;
        const float* bihl = bih + l*384;
        const float* bhhl = bhh + l*384;

        float dia[4], doa[4];
#pragma unroll
        for (int mi = 0; mi < 4; mi++) {
            int row = rowb + mi*16 + l15;
            dia[mi] = sm.degf[row][0];
            doa[mi] = sm.degf[row][1];
        }

        f32x4 acc[4][8] = {};

        // ---- K-steps 0..7: S segments ----
#pragma unroll
        for (int kt = 0; kt < 8; kt++) {
            bf16x8 b0 = LB(0,0,kt), b1 = LB(0,1,kt), b2 = LB(1,0,kt),
                   b3 = LB(1,1,kt), b4 = LB(2,0,kt), b5 = LB(2,1,kt);
            bf16x8 a_[4];
#pragma unroll
            for (int mi = 0; mi < 4; mi++) {
                int row = rowb + mi*16 + l15;
                int phys = (kt*4 + l4) ^ (row & 7);
                a_[mi] = *(const bf16x8*)((const char*)sm.S + row*512 + phys*16);
            }
#pragma unroll
            for (int mi = 0; mi < 4; mi++) {
                acc[mi][0]=MF(a_[mi],b0,acc[mi][0]); acc[mi][1]=MF(a_[mi],b1,acc[mi][1]);
                acc[mi][2]=MF(a_[mi],b2,acc[mi][2]); acc[mi][3]=MF(a_[mi],b3,acc[mi][3]);
                acc[mi][4]=MF(a_[mi],b4,acc[mi][4]); acc[mi][5]=MF(a_[mi],b5,acc[mi][5]);
            }
        }
        // ---- K-steps 8..11: indeg*h ----
#pragma unroll
        for (int kt = 8; kt < 12; kt++) {
            bf16x8 b0 = LB(0,0,kt), b1 = LB(0,1,kt), b2 = LB(1,0,kt),
                   b3 = LB(1,1,kt), b4 = LB(2,0,kt), b5 = LB(2,1,kt);
            bf16x8 a_[4];
#pragma unroll
            for (int mi = 0; mi < 4; mi++) {
                int row = rowb + mi*16 + l15;
                int phys = ((kt-8)*4 + l4) ^ (row & 7);
                bf16x8 hv = *(const bf16x8*)((const char*)sm.hreg + row*256 + phys*16);
                float s = dia[mi];
#pragma unroll
                for (int j = 0; j < 8; j++)
                    a_[mi][j] = (short)f2bf(bf2f((unsigned short)hv[j]) * s);
            }
#pragma unroll
            for (int mi = 0; mi < 4; mi++) {
                acc[mi][0]=MF(a_[mi],b0,acc[mi][0]); acc[mi][1]=MF(a_[mi],b1,acc[mi][1]);
                acc[mi][2]=MF(a_[mi],b2,acc[mi][2]); acc[mi][3]=MF(a_[mi],b3,acc[mi][3]);
                acc[mi][4]=MF(a_[mi],b4,acc[mi][4]); acc[mi][5]=MF(a_[mi],b5,acc[mi][5]);
            }
        }
        // ---- K-steps 12..15: outdeg*h ----
#pragma unroll
        for (int kt = 12; kt < 16; kt++) {
            bf16x8 b0 = LB(0,0,kt), b1 = LB(0,1,kt), b2 = LB(1,0,kt),
                   b3 = LB(1,1,kt), b4 = LB(2,0,kt), b5 = LB(2,1,kt);
            bf16x8 a_[4];
#pragma unroll
            for (int mi = 0; mi < 4; mi++) {
                int row = rowb + mi*16 + l15;
                int phys = ((kt-12)*4 + l4) ^ (row & 7);
                bf16x8 hv = *(const bf16x8*)((const char*)sm.hreg + row*256 + phys*16);
                float s = doa[mi];
#pragma unroll
                for (int j = 0; j < 8; j++)
                    a_[mi][j] = (short)f2bf(bf2f((unsigned short)hv[j]) * s);
            }
#pragma unroll
            for (int mi = 0; mi < 4; mi++) {
                acc[mi][0]=MF(a_[mi],b0,acc[mi][0]); acc[mi][1]=MF(a_[mi],b1,acc[mi][1]);
                acc[mi][2]=MF(a_[mi],b2,acc[mi][2]); acc[mi][3]=MF(a_[mi],b3,acc[mi][3]);
                acc[mi][4]=MF(a_[mi],b4,acc[mi][4]); acc[mi][5]=MF(a_[mi],b5,acc[mi][5]);
            }
        }
        // ---- K-steps 16..19: h (r/z get Whh, ghn gets Whh_n) ----
#pragma unroll
        for (int kt = 16; kt < 20; kt++) {
            bf16x8 b0 = LB(0,0,kt), b1 = LB(0,1,kt), b2 = LB(1,0,kt),
                   b3 = LB(1,1,kt), b4 = LB(3,0,kt), b5 = LB(3,1,kt);
            bf16x8 a_[4];
#pragma unroll
            for (int mi = 0; mi < 4; mi++) {
                int row = rowb + mi*16 + l15;
                int phys = ((kt-16)*4 + l4) ^ (row & 7);
                a_[mi] = *(const bf16x8*)((const char*)sm.hreg + row*256 + phys*16);
            }
#pragma unroll
            for (int mi = 0; mi < 4; mi++) {
                acc[mi][0]=MF(a_[mi],b0,acc[mi][0]); acc[mi][1]=MF(a_[mi],b1,acc[mi][1]);
                acc[mi][2]=MF(a_[mi],b2,acc[mi][2]); acc[mi][3]=MF(a_[mi],b3,acc[mi][3]);
                acc[mi][6]=MF(a_[mi],b4,acc[mi][6]); acc[mi][7]=MF(a_[mi],b5,acc[mi][7]);
            }
        }

        // ---- GRU (all in registers) ----
        f32x4 hn[4][2];
#pragma unroll
        for (int cct = 0; cct < 2; cct++) {
            int c = ch*32 + cct*16 + l15;
            float c3r = c34l[c],     c3z = c34l[128+c], c3n = c34l[256+c];
            float c4r = c34l[384+c], c4z = c34l[512+c], c4n = c34l[640+c];
            float br   = bihl[c]     + bhhl[c];
            float bz   = bihl[128+c] + bhhl[128+c];
            float bin_ = bihl[256+c];
            float bhn_ = bhhl[256+c];
#pragma unroll
            for (int mi = 0; mi < 4; mi++) {
                f32x4 R = acc[mi][cct], Z = acc[mi][2+cct];
                f32x4 GI = acc[mi][4+cct], GH = acc[mi][6+cct];
                f32x4 out;
#pragma unroll
                for (int q = 0; q < 4; q++) {
                    int row = rowb + mi*16 + l4*4 + q;
                    float di = sm.degf[row][0], dof = sm.degf[row][1];
                    float hold = bf2f(*(const unsigned short*)((const char*)sm.hreg
                                      + h_addr(row, c)));
                    float rr = sigm(R[q]  + di*c3r + dof*c4r + br);
                    float zz = sigm(Z[q]  + di*c3z + dof*c4z + bz);
                    float nn = tanh_f(GI[q] + di*c3n + dof*c4n + bin_
                                      + rr*(GH[q] + bhn_));
                    out[q] = nn + zz*(hold - nn);
                }
                hn[mi][cct] = out;
            }
        }
        __syncthreads();   // all GEMM reads of hreg/S done before rewrites
#pragma unroll
        for (int cct = 0; cct < 2; cct++) {
            int c = ch*32 + cct*16 + l15;
#pragma unroll
            for (int mi = 0; mi < 4; mi++) {
#pragma unroll
                for (int q = 0; q < 4; q++) {
                    int row = rowb + mi*16 + l4*4 + q;
                    *(unsigned short*)((char*)sm.hreg + h_addr(row, c))
                        = f2bf(hn[mi][cct][q]);
                    if (l == 1)
                        hf[(size_t)(n0 + row)*128 + c] = hn[mi][cct][q];
                }
            }
        }
        __syncthreads();
        if (l == 0) {
            gatherS(sm, tid);   // scatter for layer 1 (reads hreg=hnew)
            __syncthreads();
        }
    }

    // ---------- fused pool ----------
    if (tid < 128) {
        int row = tid;
        float a1 = 0.f, a2 = 0.f;
        for (int s = 0; s < 16; s++) {
            int phys = s ^ (row & 7);
            bf16x8 hv = *(const bf16x8*)((const char*)sm.hreg + row*256 + phys*16);
#pragma unroll
            for (int j = 0; j < 8; j++) {
                float x = bf2f((unsigned short)hv[j]);
                int c = s*8 + j;
                a1 = fmaf(gmW[c],  x, a1);
                a2 = fmaf(gmiW[c], x, a2);
            }
        }
        sm.gates[0][row] = sigm(a1 + gmb[0]);
        sm.gates[1][row] = sigm(a2 + gmib[0]);
    }
    __syncthreads();
    {
        int c = tid & 127, gq = tid >> 7;
        for (int gi2 = 0; gi2 < 2; gi2++) {
            int gl = gq + gi2*4, rb = gl*16;
            float p1 = 0.f, p2 = 0.f;
            for (int r = 0; r < 16; r++) {
                float x = bf2f(*(const unsigned short*)((const char*)sm.hreg
                               + h_addr(rb + r, c)));
                p1 = fmaf(sm.gates[0][rb + r], x, p1);
                p2 = fmaf(sm.gates[1][rb + r], x, p2);
            }
            size_t g = g0 + gl;
            P1[g*128 + c] = p1;
            P2[g*128 + c] = p2;
        }
    }
    if (tid < 16) {
        int gl = tid >> 1, w = tid & 1;
        float s = 0.f;
        for (int r = 0; r < 16; r++) s += sm.gates[w][gl*16 + r];
        sg[(size_t)(g0 + gl)*2 + w] = s;
    }
}

// ---------------------------------------------------------------------------
// Out projection: out[g][c] = fm_W[c].P[g] + fm_b[c]*sg[g].
// ---------------------------------------------------------------------------
__global__ __launch_bounds__(256) void outgemm_kernel(
    const float* __restrict__ P1, const float* __restrict__ P2,
    const float* __restrict__ sg,
    const float* __restrict__ fm_W,  const float* __restrict__ fm_b,
    const float* __restrict__ fmi_W, const float* __restrict__ fmi_b,
    float* __restrict__ out1, float* __restrict__ out2)
{
    const int g0 = blockIdx.x * 32;
    const int t  = threadIdx.x;
    __shared__ float Ws[128][33];
    __shared__ float Ps[32][33];
    const int tc = t & 15, tg = t >> 4;

    for (int pass = 0; pass < 2; pass++) {
        const float* P  = pass ? P2 : P1;
        const float* W  = pass ? fmi_W : fm_W;
        const float* bb = pass ? fmi_b : fm_b;
        float acc[2][8] = {};
        for (int kc = 0; kc < 128; kc += 32) {
#pragma unroll
            for (int i = 0; i < 16; i++) {
                int u = i*256 + t; int r = u >> 5, k = u & 31;
                Ws[r][k] = W[(size_t)r*128 + kc + k];
            }
#pragma unroll
            for (int i = 0; i < 4; i++) {
                int u = i*256 + t; int r = u >> 5, k = u & 31;
                Ps[r][k] = P[(size_t)(g0 + r)*128 + kc + k];
            }
            __syncthreads();
#pragma unroll 8
            for (int k = 0; k < 32; k++) {
                float p0 = Ps[tg*2][k], p1v = Ps[tg*2+1][k];
#pragma unroll
                for (int j = 0; j < 8; j++) {
                    float w = Ws[tc*8+j][k];
                    acc[0][j] = fmaf(p0,  w, acc[0][j]);
                    acc[1][j] = fmaf(p1v, w, acc[1][j]);
                }
            }
            __syncthreads();
        }
        float* outp = pass ? out2 : out1;
#pragma unroll
        for (int i = 0; i < 2; i++) {
            int g = g0 + tg*2 + i;
            float sgv = sg[g*2 + pass];
#pragma unroll
            for (int j = 0; j < 8; j++) {
                int cc = tc*8 + j;
                outp[(size_t)g*128 + cc] = acc[i][j] + bb[cc]*sgv;
            }
        }
    }
}

// ---------------------------------------------------------------------------
extern "C" void kernel_launch(void* const* d_in, const int* in_sizes, int n_in,
                              void* d_out, int out_size, void* d_ws, size_t ws_size,
                              hipStream_t stream)
{
    const float* h     = (const float*)d_in[0];
    const int*   ei    = (const int*)d_in[1];
    const float* msgW  = (const float*)d_in[2];
    const float* msgb  = (const float*)d_in[3];
    const float* msgrW = (const float*)d_in[4];
    const float* msgrb = (const float*)d_in[5];
    const float* Wih   = (const float*)d_in[6];
    const float* Whh   = (const float*)d_in[7];
    const float* bih   = (const float*)d_in[8];
    const float* bhh   = (const float*)d_in[9];
    const float* fmW   = (const float*)d_in[10];
    const float* fmb   = (const float*)d_in[11];
    const float* gmW   = (const float*)d_in[12];
    const float* gmb   = (const float*)d_in[13];
    const float* fmiW  = (const float*)d_in[14];
    const float* fmib  = (const float*)d_in[15];
    const float* gmiW  = (const float*)d_in[16];
    const float* gmib  = (const float*)d_in[17];

    char* w = (char*)d_ws;
    unsigned short* WB = (unsigned short*)w;  w += (size_t)2*512*640*2;  // 1.31 MB
    float* c34   = (float*)w;                 w += (size_t)2*768*4;
    float* P1    = (float*)w;                 w += (size_t)B_GRAPHS*128*4;
    float* P2    = (float*)w;                 w += (size_t)B_GRAPHS*128*4;
    float* sgb   = (float*)w;                 w += (size_t)B_GRAPHS*2*4;

    float* hf   = (float*)d_out;
    float* out1 = hf + (size_t)NN*128;
    float* out2 = out1 + (size_t)B_GRAPHS*128;

    int compose_items = 2*512*640 + 2*2*384;
    compose_kernel<<<(compose_items + 255)/256, 256, 0, stream>>>(
        msgW, msgrW, Wih, Whh, msgb, msgrb, WB, c34);

    mega_kernel<<<NN/128, 512, 0, stream>>>(
        h, ei, WB, c34, bih, bhh, gmW, gmb, gmiW, gmib, hf, P1, P2, sgb);

    outgemm_kernel<<<B_GRAPHS/32, 256, 0, stream>>>(
        P1, P2, sgb, fmW, fmb, fmiW, fmib, out1, out2);
}

// Round 6
// 738.126 us; speedup vs baseline: 1.0489x; 1.0489x over previous
//
#include <hip/hip_runtime.h>
#include <math.h>
#include <stdint.h>

#define NDIM 128
#define B_GRAPHS 8192
#define IDX 16
#define EPG 32
#define NN (B_GRAPHS*IDX)      // 131072 nodes
#define NE (B_GRAPHS*EPG)      // 262144 edges

typedef short bf16x8 __attribute__((ext_vector_type(8)));
typedef float f32x4  __attribute__((ext_vector_type(4)));
typedef unsigned short u16x4 __attribute__((ext_vector_type(4)));

__device__ inline unsigned short f2bf(float x) {
    union { float f; unsigned u; } v; v.f = x;
    unsigned r = v.u + 0x7fff + ((v.u >> 16) & 1);
    return (unsigned short)(r >> 16);
}
__device__ inline float bf2f(unsigned short b) {
    union { unsigned u; float f; } v; v.u = ((unsigned)b) << 16;
    return v.f;
}
__device__ inline float sigm(float x) { return 1.f/(1.f + __expf(-x)); }
__device__ inline float tanh_f(float x) {
    float ax = fabsf(x);
    float t  = __expf(-2.f*ax);
    float r  = (1.f - t)/(1.f + t);
    return copysignf(r, x);
}

#define GLOAD_LDS16(g, l) \
    __builtin_amdgcn_global_load_lds( \
        (const __attribute__((address_space(1))) unsigned int*)(g), \
        (__attribute__((address_space(3))) unsigned int*)(l), 16, 0, 0)

// ---------------------------------------------------------------------------
// Compose bf16 weight matrix WB[l][col'][k] (512 cols x 640 K) and c34.
// K segments: [S_in(128)|S_out(128)|indeg*h(128)|outdeg*h(128)|h(128)]
// Column interleave: col' = (c>>4)*64 + type*16 + (c&15), type in {r,z,gin,ghn}
// -> each 64-col' group = 16 channels x all 4 types (one wave's stripe).
// ---------------------------------------------------------------------------
__global__ __launch_bounds__(256) void compose_kernel(
    const float* __restrict__ msg_W, const float* __restrict__ msgr_W,
    const float* __restrict__ Wih,   const float* __restrict__ Whh,
    const float* __restrict__ msg_b, const float* __restrict__ msgr_b,
    unsigned short* __restrict__ WB, float* __restrict__ c34)
{
    int idx = blockIdx.x*256 + threadIdx.x;
    const int TWB = 2*512*640;
    if (idx < TWB) {
        int l = idx / (512*640); int rem = idx - l*(512*640);
        int cold = rem / 640; int k = rem - cold*640;
        float val;
        if (k < 512) {
            if (cold < 384) {
                const float* wih = Wih + l*384*256 + cold*256;
                const float* M; int sc;
                if (k < 128)      { M = msg_W  + l*256*256; sc = k;       }
                else if (k < 256) { M = msgr_W + l*256*256; sc = k - 128; }
                else if (k < 384) { M = msg_W  + l*256*256; sc = k - 128; }
                else              { M = msgr_W + l*256*256; sc = k - 256; }
                float acc = 0.f;
                for (int q = 0; q < 256; q++) acc = fmaf(wih[q], M[q*256 + sc], acc);
                val = acc;
            } else val = 0.f;
        } else {
            int kk = k - 512;
            if (cold < 256)      val = Whh[l*384*128 + cold*128 + kk];
            else if (cold < 384) val = 0.f;
            else                 val = Whh[l*384*128 + (cold-128)*128 + kk];
        }
        int cc = cold & 127, t = cold >> 7;
        int colp = ((cc >> 4) << 6) + (t << 4) + (cc & 15);
        WB[l*512*640 + colp*640 + k] = f2bf(val);
    } else if (idx < TWB + 2*2*384) {
        int i2 = idx - TWB;
        int l = i2 / 768; int rem = i2 - l*768;
        int which = rem / 384; int r = rem - which*384;
        const float* wih = Wih + l*384*256 + r*256;
        const float* bb  = (which ? msgr_b : msg_b) + l*256;
        float acc = 0.f;
        for (int q = 0; q < 256; q++) acc = fmaf(wih[q], bb[q], acc);
        c34[l*768 + which*384 + r] = acc;
    }
}

// ---------------------------------------------------------------------------
// Mega kernel LDS. 151 KB total, 1 block/CU.
// ---------------------------------------------------------------------------
struct MegaSmem {
    union R0 {
        unsigned short S[128*256];                       // 64 KB (K-steps 0-7)
        struct { unsigned short dih[128*128];            // aliased after step 7
                 unsigned short doh[128*128]; } d;
    } r0;
    unsigned short hreg[128*128];                        // 32 KB
    unsigned short Bbuf[2][384*32];                      // 48 KB (384 active cols)
    unsigned char sl8[256], dl8[256];
    unsigned char csr[8][2][17];
    unsigned char adj[8][2][32];
    unsigned char off[8][2][16];
    float degf[128][2];
    float gates[2][128];
    int flag64;
};

__device__ __forceinline__ int s_addr(int row, int e) {
    return row*512 + (((e>>3) ^ (row&7))<<4) + ((e&7)<<1);
}
__device__ __forceinline__ int h_addr(int row, int c) {
    return row*256 + (((c>>3) ^ (row&7))<<4) + ((c&7)<<1);
}

__device__ __forceinline__ void gatherS(MegaSmem& sm, int tid) {
    int c = tid & 127, gq = tid >> 7;
#pragma unroll
    for (int gi2 = 0; gi2 < 2; gi2++) {
        int gl = gq + gi2*4, rb = gl*16;
        for (int d = 0; d < 16; d++) {
            float a = 0.f;
            int s0 = sm.csr[gl][0][d], s1 = sm.csr[gl][0][d+1];
            for (int j = s0; j < s1; j++)
                a += bf2f(*(const unsigned short*)((const char*)sm.hreg
                        + h_addr(rb + sm.adj[gl][0][j], c)));
            *(unsigned short*)((char*)sm.r0.S + s_addr(rb + d, c)) = f2bf(a);
            float b = 0.f;
            s0 = sm.csr[gl][1][d]; s1 = sm.csr[gl][1][d+1];
            for (int j = s0; j < s1; j++)
                b += bf2f(*(const unsigned short*)((const char*)sm.hreg
                        + h_addr(rb + sm.adj[gl][1][j], c)));
            *(unsigned short*)((char*)sm.r0.S + s_addr(rb + d, 128 + c)) = f2bf(b);
        }
    }
}

#define MF(a,b,c) __builtin_amdgcn_mfma_f32_16x16x32_bf16((a),(b),(c),0,0,0)

// One K-step: 3 B-frags (active types) + 8 A-frags, 24 MFMA. J2 = acc col for
// the third active type (2 = gin for ks<16, 3 = ghn for ks>=16). Static idx.
#define CSTEP(ABASE, RSH, SLOTB, BUF, J2) do {                                  \
    bf16x8 _bf0, _bf1, _bf2;                                                    \
    { int a0 = wid*48 + l15;                                                    \
      _bf0 = *(const bf16x8*)((const char*)sm.Bbuf[BUF] + a0*64                 \
              + ((l4 ^ ((a0>>2)&3))<<4)); }                                     \
    { int a1 = wid*48 + 16 + l15;                                               \
      _bf1 = *(const bf16x8*)((const char*)sm.Bbuf[BUF] + a1*64                 \
              + ((l4 ^ ((a1>>2)&3))<<4)); }                                     \
    { int a2 = wid*48 + 32 + l15;                                               \
      _bf2 = *(const bf16x8*)((const char*)sm.Bbuf[BUF] + a2*64                 \
              + ((l4 ^ ((a2>>2)&3))<<4)); }                                     \
    _Pragma("unroll")                                                           \
    for (int mi = 0; mi < 8; mi++) {                                            \
        int row = mi*16 + l15;                                                  \
        int phys = ((SLOTB) + l4) ^ (row & 7);                                  \
        bf16x8 _af = *(const bf16x8*)((const char*)(ABASE)                      \
                      + (row << (RSH)) + (phys << 4));                          \
        acc[mi][0]  = MF(_af, _bf0, acc[mi][0]);                                \
        acc[mi][1]  = MF(_af, _bf1, acc[mi][1]);                                \
        acc[mi][J2] = MF(_af, _bf2, acc[mi][J2]);                               \
    }                                                                           \
} while (0)

__global__ __launch_bounds__(512, 2) void mega_kernel(
    const float* __restrict__ hin, const int* __restrict__ ei,
    const unsigned short* __restrict__ WB, const float* __restrict__ c34,
    const float* __restrict__ bih, const float* __restrict__ bhh,
    const float* __restrict__ gmW,  const float* __restrict__ gmb,
    const float* __restrict__ gmiW, const float* __restrict__ gmib,
    float* __restrict__ hf, float* __restrict__ P1, float* __restrict__ P2,
    float* __restrict__ sg)
{
    __shared__ MegaSmem sm;
    const int n0  = blockIdx.x * 128;
    const int g0  = blockIdx.x * 8;
    const int tid = threadIdx.x;
    const int lane = tid & 63, wid = tid >> 6;     // wave owns 16 channels
    const int l15 = lane & 15, l4 = lane >> 4;

    // ---------- stage-address precompute (384 active cols, 3 loads/thread) --
    int bc0[3], bc1[3], bso[3], bdst[3];
#pragma unroll
    for (int i = 0; i < 3; i++) {
        int u = i*512 + tid;
        int a = u >> 2, s = u & 3;
        int chh = a / 48;
        int rem = a - chh*48;
        int tt = rem >> 4, clo = rem & 15;
        bc0[i] = chh*64 + tt*16 + clo;                    // ks < 16: types 0,1,2
        bc1[i] = chh*64 + ((tt==2) ? 48 : tt*16) + clo;   // ks >=16: types 0,1,3
        bso[i] = (s ^ ((a >> 2) & 3)) * 8;                // u16 offset (swizzled src)
        bdst[i] = u * 8;                                  // u16 offset (linear dst)
    }

    // ---------- init: h -> LDS (bf16 swizzled), float4 loads ----------
    if (tid == 0) {
        int orv = 0;
        for (int i = 1; i < 64; i += 2) orv |= ei[i];
        sm.flag64 = (orv == 0);
    }
    const float4* hin4 = (const float4*)(hin + (size_t)n0*128);
#pragma unroll
    for (int i = 0; i < 8; i++) {
        int idx = i*512 + tid; int row = idx >> 5, c4 = idx & 31, c0 = c4*4;
        float4 hv = hin4[idx];
        u16x4 w; w[0]=f2bf(hv.x); w[1]=f2bf(hv.y); w[2]=f2bf(hv.z); w[3]=f2bf(hv.w);
        *(u16x4*)((char*)sm.hreg + h_addr(row, c0)) = w;
    }
    __syncthreads();
    // ---------- edge decode ----------
    if (tid < 256) {
        int gl = tid >> 5;
        int e = (g0 + gl)*32 + (tid & 31);
        int sv, dv;
        if (sm.flag64) { sv = ei[2*e]; dv = ei[2*(NE + e)]; }
        else           { sv = ei[e];   dv = ei[NE + e];     }
        sm.sl8[tid] = (unsigned char)(sv - (g0 + gl)*16);
        sm.dl8[tid] = (unsigned char)(dv - (g0 + gl)*16);
    }
    __syncthreads();
    if (tid < 16) {   // CSR build (counting sort)
        int gl = tid >> 1, dir = tid & 1;
        const unsigned char* key = dir ? sm.sl8 : sm.dl8;
        const unsigned char* val = dir ? sm.dl8 : sm.sl8;
        unsigned char* C = sm.csr[gl][dir];
        for (int d = 0; d < 17; d++) C[d] = 0;
        for (int e2 = 0; e2 < 32; e2++) C[key[gl*32 + e2] + 1]++;
        for (int d = 0; d < 16; d++) { C[d+1] += C[d]; sm.off[gl][dir][d] = C[d]; }
        for (int e2 = 0; e2 < 32; e2++) {
            int k = key[gl*32 + e2];
            sm.adj[gl][dir][sm.off[gl][dir][k]++] = val[gl*32 + e2];
        }
    }
    __syncthreads();
    if (tid < 128) {
        int gl = tid >> 4, d = tid & 15;
        sm.degf[tid][0] = (float)(sm.csr[gl][0][d+1] - sm.csr[gl][0][d]);
        sm.degf[tid][1] = (float)(sm.csr[gl][1][d+1] - sm.csr[gl][1][d]);
    }
    __syncthreads();
    gatherS(sm, tid);
    __syncthreads();

    // ---------- two GNN layers ----------
    for (int l = 0; l < 2; l++) {
        const unsigned short* WBl = WB + (size_t)l*512*640;
        const float* c34l = c34 + l*768;
        const float* bihl = bih + l*384;
        const float* bhhl = bhh + l*384;

        auto STAGE = [&](int ks, int b) {
            const unsigned short* base = WBl + ks*32;
#pragma unroll
            for (int i = 0; i < 3; i++) {
                int colp = (ks < 16) ? bc0[i] : bc1[i];
                GLOAD_LDS16(base + (size_t)colp*640 + bso[i],
                            sm.Bbuf[b] + bdst[i]);
            }
        };

        f32x4 acc[8][4];
#pragma unroll
        for (int mi = 0; mi < 8; mi++)
#pragma unroll
            for (int ni = 0; ni < 4; ni++) acc[mi][ni] = (f32x4){0.f,0.f,0.f,0.f};

        STAGE(0, 0);
        __syncthreads();
        // ---- K-steps 0..7: S segments ----
#pragma unroll
        for (int ks = 0; ks < 8; ks++) {
            STAGE(ks+1, (ks+1)&1);
            CSTEP((const char*)sm.r0.S, 9, ks*4, ks&1, 2);
            __syncthreads();
        }
        // ---- build dih/doh into r0 (S dead); stage(9) early to keep pipe ----
        STAGE(9, 1);
        {
            int c = tid & 127, rb = (tid >> 7) * 32;
#pragma unroll 4
            for (int r = 0; r < 32; r++) {
                int row = rb + r;
                int off = h_addr(row, c);
                float f = bf2f(*(const unsigned short*)((const char*)sm.hreg + off));
                *(unsigned short*)((char*)sm.r0.d.dih + off) = f2bf(f*sm.degf[row][0]);
                *(unsigned short*)((char*)sm.r0.d.doh + off) = f2bf(f*sm.degf[row][1]);
            }
        }
        __syncthreads();
        CSTEP((const char*)sm.r0.d.dih, 8, 0, 0, 2);   // ks=8
        __syncthreads();
#pragma unroll
        for (int ks = 9; ks < 12; ks++) {
            STAGE(ks+1, (ks+1)&1);
            CSTEP((const char*)sm.r0.d.dih, 8, (ks-8)*4, ks&1, 2);
            __syncthreads();
        }
#pragma unroll
        for (int ks = 12; ks < 16; ks++) {
            STAGE(ks+1, (ks+1)&1);
            CSTEP((const char*)sm.r0.d.doh, 8, (ks-12)*4, ks&1, 2);
            __syncthreads();
        }
#pragma unroll
        for (int ks = 16; ks < 20; ks++) {
            if (ks < 19) STAGE(ks+1, (ks+1)&1);
            CSTEP((const char*)sm.hreg, 8, (ks-16)*4, ks&1, 3);
            __syncthreads();
        }

        // ---- GRU: thread owns channel c, 32 rows; read+write own cells ----
        {
            int c = wid*16 + l15;
            float c3r = c34l[c],     c3z = c34l[128+c], c3n = c34l[256+c];
            float c4r = c34l[384+c], c4z = c34l[512+c], c4n = c34l[640+c];
            float br   = bihl[c]     + bhhl[c];
            float bz   = bihl[128+c] + bhhl[128+c];
            float bin_ = bihl[256+c];
            float bhn_ = bhhl[256+c];
#pragma unroll
            for (int mi = 0; mi < 8; mi++) {
#pragma unroll
                for (int q = 0; q < 4; q++) {
                    int row = mi*16 + l4*4 + q;
                    int off = h_addr(row, c);
                    float di = sm.degf[row][0], dof = sm.degf[row][1];
                    float hold = bf2f(*(const unsigned short*)((const char*)sm.hreg + off));
                    float rr = sigm(acc[mi][0][q] + di*c3r + dof*c4r + br);
                    float zz = sigm(acc[mi][1][q] + di*c3z + dof*c4z + bz);
                    float nn = tanh_f(acc[mi][2][q] + di*c3n + dof*c4n + bin_
                                      + rr*(acc[mi][3][q] + bhn_));
                    float hv = nn + zz*(hold - nn);
                    *(unsigned short*)((char*)sm.hreg + off) = f2bf(hv);
                    if (l == 1) hf[(size_t)(n0 + row)*128 + c] = hv;
                }
            }
        }
        __syncthreads();
        if (l == 0) {
            gatherS(sm, tid);   // rebuild S from new h for layer 1
            __syncthreads();
        }
    }

    // ---------- fused pool ----------
    if (tid < 128) {
        int row = tid;
        float a1 = 0.f, a2 = 0.f;
        for (int s = 0; s < 16; s++) {
            int phys = s ^ (row & 7);
            bf16x8 hv = *(const bf16x8*)((const char*)sm.hreg + row*256 + phys*16);
#pragma unroll
            for (int j = 0; j < 8; j++) {
                float x = bf2f((unsigned short)hv[j]);
                int c = s*8 + j;
                a1 = fmaf(gmW[c],  x, a1);
                a2 = fmaf(gmiW[c], x, a2);
            }
        }
        sm.gates[0][row] = sigm(a1 + gmb[0]);
        sm.gates[1][row] = sigm(a2 + gmib[0]);
    }
    __syncthreads();
    {
        int c = tid & 127, gq = tid >> 7;
#pragma unroll
        for (int gi2 = 0; gi2 < 2; gi2++) {
            int gl = gq + gi2*4, rb = gl*16;
            float p1 = 0.f, p2 = 0.f;
            for (int r = 0; r < 16; r++) {
                float x = bf2f(*(const unsigned short*)((const char*)sm.hreg
                               + h_addr(rb + r, c)));
                p1 = fmaf(sm.gates[0][rb + r], x, p1);
                p2 = fmaf(sm.gates[1][rb + r], x, p2);
            }
            size_t g = g0 + gl;
            P1[g*128 + c] = p1;
            P2[g*128 + c] = p2;
        }
    }
    if (tid < 16) {
        int gl = tid >> 1, w = tid & 1;
        float s = 0.f;
        for (int r = 0; r < 16; r++) s += sm.gates[w][gl*16 + r];
        sg[(size_t)(g0 + gl)*2 + w] = s;
    }
}

// ---------------------------------------------------------------------------
// Out projection: out[g][c] = fm_W[c].P[g] + fm_b[c]*sg[g].
// ---------------------------------------------------------------------------
__global__ __launch_bounds__(256) void outgemm_kernel(
    const float* __restrict__ P1, const float* __restrict__ P2,
    const float* __restrict__ sg,
    const float* __restrict__ fm_W,  const float* __restrict__ fm_b,
    const float* __restrict__ fmi_W, const float* __restrict__ fmi_b,
    float* __restrict__ out1, float* __restrict__ out2)
{
    const int g0 = blockIdx.x * 32;
    const int t  = threadIdx.x;
    __shared__ float Ws[128][33];
    __shared__ float Ps[32][33];
    const int tc = t & 15, tg = t >> 4;

    for (int pass = 0; pass < 2; pass++) {
        const float* P  = pass ? P2 : P1;
        const float* W  = pass ? fmi_W : fm_W;
        const float* bb = pass ? fmi_b : fm_b;
        float acc[2][8] = {};
        for (int kc = 0; kc < 128; kc += 32) {
#pragma unroll
            for (int i = 0; i < 16; i++) {
                int u = i*256 + t; int r = u >> 5, k = u & 31;
                Ws[r][k] = W[(size_t)r*128 + kc + k];
            }
#pragma unroll
            for (int i = 0; i < 4; i++) {
                int u = i*256 + t; int r = u >> 5, k = u & 31;
                Ps[r][k] = P[(size_t)(g0 + r)*128 + kc + k];
            }
            __syncthreads();
#pragma unroll 8
            for (int k = 0; k < 32; k++) {
                float p0 = Ps[tg*2][k], p1v = Ps[tg*2+1][k];
#pragma unroll
                for (int j = 0; j < 8; j++) {
                    float w = Ws[tc*8+j][k];
                    acc[0][j] = fmaf(p0,  w, acc[0][j]);
                    acc[1][j] = fmaf(p1v, w, acc[1][j]);
                }
            }
            __syncthreads();
        }
        float* outp = pass ? out2 : out1;
#pragma unroll
        for (int i = 0; i < 2; i++) {
            int g = g0 + tg*2 + i;
            float sgv = sg[g*2 + pass];
#pragma unroll
            for (int j = 0; j < 8; j++) {
                int cc = tc*8 + j;
                outp[(size_t)g*128 + cc] = acc[i][j] + bb[cc]*sgv;
            }
        }
    }
}

// ---------------------------------------------------------------------------
extern "C" void kernel_launch(void* const* d_in, const int* in_sizes, int n_in,
                              void* d_out, int out_size, void* d_ws, size_t ws_size,
                              hipStream_t stream)
{
    const float* h     = (const float*)d_in[0];
    const int*   ei    = (const int*)d_in[1];
    const float* msgW  = (const float*)d_in[2];
    const float* msgb  = (const float*)d_in[3];
    const float* msgrW = (const float*)d_in[4];
    const float* msgrb = (const float*)d_in[5];
    const float* Wih   = (const float*)d_in[6];
    const float* Whh   = (const float*)d_in[7];
    const float* bih   = (const float*)d_in[8];
    const float* bhh   = (const float*)d_in[9];
    const float* fmW   = (const float*)d_in[10];
    const float* fmb   = (const float*)d_in[11];
    const float* gmW   = (const float*)d_in[12];
    const float* gmb   = (const float*)d_in[13];
    const float* fmiW  = (const float*)d_in[14];
    const float* fmib  = (const float*)d_in[15];
    const float* gmiW  = (const float*)d_in[16];
    const float* gmib  = (const float*)d_in[17];

    char* w = (char*)d_ws;
    unsigned short* WB = (unsigned short*)w;  w += (size_t)2*512*640*2;  // 1.31 MB
    float* c34   = (float*)w;                 w += (size_t)2*768*4;
    float* P1    = (float*)w;                 w += (size_t)B_GRAPHS*128*4;
    float* P2    = (float*)w;                 w += (size_t)B_GRAPHS*128*4;
    float* sgb   = (float*)w;                 w += (size_t)B_GRAPHS*2*4;

    float* hf   = (float*)d_out;
    float* out1 = hf + (size_t)NN*128;
    float* out2 = out1 + (size_t)B_GRAPHS*128;

    int compose_items = 2*512*640 + 2*2*384;
    compose_kernel<<<(compose_items + 255)/256, 256, 0, stream>>>(
        msgW, msgrW, Wih, Whh, msgb, msgrb, WB, c34);

    mega_kernel<<<NN/128, 512, 0, stream>>>(
        h, ei, WB, c34, bih, bhh, gmW, gmb, gmiW, gmib, hf, P1, P2, sgb);

    outgemm_kernel<<<B_GRAPHS/32, 256, 0, stream>>>(
        P1, P2, sgb, fmW, fmb, fmiW, fmib, out1, out2);
}

// Round 7
// 438.884 us; speedup vs baseline: 1.7640x; 1.6818x over previous
//
#include <hip/hip_runtime.h>
#include <math.h>
#include <stdint.h>

#define NDIM 128
#define B_GRAPHS 8192
#define IDX 16
#define EPG 32
#define NN (B_GRAPHS*IDX)      // 131072 nodes
#define NE (B_GRAPHS*EPG)      // 262144 edges

typedef short bf16x8 __attribute__((ext_vector_type(8)));
typedef float f32x4  __attribute__((ext_vector_type(4)));

__device__ inline unsigned short f2bf(float x) {
    union { float f; unsigned u; } v; v.f = x;
    unsigned r = v.u + 0x7fff + ((v.u >> 16) & 1);
    return (unsigned short)(r >> 16);
}
__device__ inline float bf2f(unsigned short b) {
    union { unsigned u; float f; } v; v.u = ((unsigned)b) << 16;
    return v.f;
}
__device__ inline float sigm(float x) { return 1.f/(1.f + __expf(-x)); }
__device__ inline float tanh_f(float x) {
    float ax = fabsf(x);
    float t  = __expf(-2.f*ax);
    float r  = (1.f - t)/(1.f + t);
    return copysignf(r, x);
}

#define GLOAD_LDS16(g, l) \
    __builtin_amdgcn_global_load_lds( \
        (const __attribute__((address_space(1))) unsigned int*)(g), \
        (__attribute__((address_space(3))) unsigned int*)(l), 16, 0, 0)

// ---------------------------------------------------------------------------
// Compose bf16 weight matrix WB[l][col'][k] (512 cols x 640 K) and c34.
// K segments: [S_in(128)|S_out(128)|indeg*h(128)|outdeg*h(128)|h(128)]
// Column interleave: col' = (c>>4)*64 + type*16 + (c&15), type in {r,z,gin,ghn}
// -> each 64-col' group = 16 channels x all 4 types (one wave's stripe).
// ---------------------------------------------------------------------------
__global__ __launch_bounds__(256) void compose_kernel(
    const float* __restrict__ msg_W, const float* __restrict__ msgr_W,
    const float* __restrict__ Wih,   const float* __restrict__ Whh,
    const float* __restrict__ msg_b, const float* __restrict__ msgr_b,
    unsigned short* __restrict__ WB, float* __restrict__ c34)
{
    int idx = blockIdx.x*256 + threadIdx.x;
    const int TWB = 2*512*640;
    if (idx < TWB) {
        int l = idx / (512*640); int rem = idx - l*(512*640);
        int cold = rem / 640; int k = rem - cold*640;
        float val;
        if (k < 512) {
            if (cold < 384) {
                const float* wih = Wih + l*384*256 + cold*256;
                const float* M; int sc;
                if (k < 128)      { M = msg_W  + l*256*256; sc = k;       }
                else if (k < 256) { M = msgr_W + l*256*256; sc = k - 128; }
                else if (k < 384) { M = msg_W  + l*256*256; sc = k - 128; }
                else              { M = msgr_W + l*256*256; sc = k - 256; }
                float acc = 0.f;
                for (int q = 0; q < 256; q++) acc = fmaf(wih[q], M[q*256 + sc], acc);
                val = acc;
            } else val = 0.f;
        } else {
            int kk = k - 512;
            if (cold < 256)      val = Whh[l*384*128 + cold*128 + kk];
            else if (cold < 384) val = 0.f;
            else                 val = Whh[l*384*128 + (cold-128)*128 + kk];
        }
        int cc = cold & 127, t = cold >> 7;
        int colp = ((cc >> 4) << 6) + (t << 4) + (cc & 15);
        WB[l*512*640 + colp*640 + k] = f2bf(val);
    } else if (idx < TWB + 2*2*384) {
        int i2 = idx - TWB;
        int l = i2 / 768; int rem = i2 - l*768;
        int which = rem / 384; int r = rem - which*384;
        const float* wih = Wih + l*384*256 + r*256;
        const float* bb  = (which ? msgr_b : msg_b) + l*256;
        float acc = 0.f;
        for (int q = 0; q < 256; q++) acc = fmaf(wih[q], bb[q], acc);
        c34[l*768 + which*384 + r] = acc;
    }
}

// ---------------------------------------------------------------------------
// Init: per-graph edge decode + degree + packed edges + A0 build (bf16).
// A[v] = [S_in | S_out | indeg*h | outdeg*h | h]   (proven rounds 2-4)
// ---------------------------------------------------------------------------
__global__ __launch_bounds__(128) void init_kernel(
    const float* __restrict__ hin, const int* __restrict__ ei,
    unsigned short* __restrict__ A, float* __restrict__ indeg,
    float* __restrict__ outdeg, unsigned char* __restrict__ pack)
{
    int g = blockIdx.x, t = threadIdx.x;
    __shared__ float hb[16][128];
    __shared__ float sin_[16][128];
    __shared__ float sout_[16][128];
    __shared__ int sl[32], dl[32];
    __shared__ int cin[16], cout[16];
    __shared__ int flag64;
    int base = g*IDX;
    for (int r = 0; r < 16; r++) hb[r][t] = hin[(size_t)(base+r)*128 + t];
    for (int r = 0; r < 16; r++) { sin_[r][t] = 0.f; sout_[r][t] = 0.f; }
    if (t < 16) { cin[t] = 0; cout[t] = 0; }
    if (t == 0) {
        int orv = 0;
        for (int i = 1; i < 64; i += 2) orv |= ei[i];
        flag64 = (orv == 0);
    }
    __syncthreads();
    if (t < 32) {
        int e = g*EPG + t;
        int sv, dv;
        if (flag64) { sv = ei[2*e]; dv = ei[2*(NE + e)]; }
        else        { sv = ei[e];   dv = ei[NE + e];     }
        sl[t] = sv - base; dl[t] = dv - base;
        atomicAdd(&cout[sl[t]], 1); atomicAdd(&cin[dl[t]], 1);
        pack[g*32 + t] = (unsigned char)((sl[t] & 15) | ((dl[t] & 15) << 4));
    }
    __syncthreads();
    for (int e = 0; e < 32; e++) {
        sin_[dl[e]][t]  += hb[sl[e]][t];
        sout_[sl[e]][t] += hb[dl[e]][t];
    }
    for (int r = 0; r < 16; r++) {
        size_t v = base + r;
        float di = (float)cin[r], dof = (float)cout[r];
        A[v*640 + t]        = f2bf(sin_[r][t]);
        A[v*640 + 128 + t]  = f2bf(sout_[r][t]);
        A[v*640 + 256 + t]  = f2bf(di  * hb[r][t]);
        A[v*640 + 384 + t]  = f2bf(dof * hb[r][t]);
        A[v*640 + 512 + t]  = f2bf(hb[r][t]);
    }
    if (t < 16) { indeg[base+t] = (float)cin[t]; outdeg[base+t] = (float)cout[t]; }
}

// ---------------------------------------------------------------------------
// Fused GEMM+GRU (+scatter / +pool). Round-4 skeleton:
//  - block = 128 rows (8 graphs) x all 512 cols, 8 waves
//  - 3-deep global_load_lds pipeline, runtime K-loop, vmcnt(4) counted waits
//  - interleaved WB: wave owns 16 channels x 4 types -> GRU in registers
//  - stage only 384 active cols/step (24 balanced MFMA/wave/step)
//  - !FINAL: CSR-gather scatter rewrites A (own rows only - race-free)
//  - FINAL: writes hf + fused gated pooling (P1/P2/sg)
// ---------------------------------------------------------------------------
struct FSmem {
    unsigned short As[3][128*32];          // 24 KB
    union {
        unsigned short Bs[3][384*32];      // 72 KB (K-loop)
        unsigned short hnewB[128*128];     // 32 KB (epilogue, h_addr swizzle)
    } u;
    unsigned char csr[8][2][17];
    unsigned char adj[8][2][32];
    unsigned char offj[8][2][16];
    float gates[2][128];
};

__device__ __forceinline__ int h_addr(int row, int c) {
    return row*256 + (((c>>3) ^ (row&7))<<4) + ((c&7)<<1);
}

#define MF(a,b,c) __builtin_amdgcn_mfma_f32_16x16x32_bf16((a),(b),(c),0,0,0)

// one K-step: 3 B-frags + 8 A-frags, 24 MFMA. J2 literal: 2 (gin) or 3 (ghn).
#define CSTEP(BUF, J2) do {                                                   \
    const unsigned short* Asb = sm.As[BUF];                                   \
    const unsigned short* Bsb = sm.u.Bs[BUF];                                 \
    bf16x8 bfv[3];                                                            \
    _Pragma("unroll")                                                         \
    for (int t = 0; t < 3; t++) {                                             \
        int a0 = wid*48 + t*16 + l15;                                         \
        bfv[t] = *(const bf16x8*)(Bsb + a0*32 + (l4 ^ ((a0>>2)&3))*8);        \
    }                                                                         \
    _Pragma("unroll")                                                         \
    for (int mi = 0; mi < 8; mi++) {                                          \
        int row = mi*16 + l15;                                                \
        bf16x8 af = *(const bf16x8*)(Asb + row*32 + (l4 ^ ((row>>2)&3))*8);   \
        acc[mi][0]  = MF(af, bfv[0], acc[mi][0]);                             \
        acc[mi][1]  = MF(af, bfv[1], acc[mi][1]);                             \
        acc[mi][J2] = MF(af, bfv[2], acc[mi][J2]);                            \
    }                                                                         \
} while (0)

template <bool FINAL>
__global__ __launch_bounds__(512, 2) void fused_kernel(
    unsigned short* __restrict__ A,
    const unsigned short* __restrict__ WBl,
    const float* __restrict__ indeg, const float* __restrict__ outdeg,
    const unsigned char* __restrict__ pack,
    const float* __restrict__ c34l,
    const float* __restrict__ bihl, const float* __restrict__ bhhl,
    const float* __restrict__ gmW,  const float* __restrict__ gmb,
    const float* __restrict__ gmiW, const float* __restrict__ gmib,
    float* __restrict__ hf, float* __restrict__ P1, float* __restrict__ P2,
    float* __restrict__ sg)
{
    __shared__ FSmem sm;
    const int n0  = blockIdx.x * 128;
    const int g0  = blockIdx.x * 8;
    const int tid = threadIdx.x;
    const int lane = tid & 63, wid = tid >> 6;   // wave owns 16 channels
    const int l15 = lane & 15, l4 = lane >> 4;

    // staging address precompute. A: 1 unit/thread; B: 3 units/thread.
    const int arow = tid >> 2, as_ = tid & 3;
    const int asrc = (as_ ^ ((arow >> 2) & 3)) * 8;
    const int adst = tid * 8;
    int bcol0[3], bcol1[3], bsrc[3], bdst[3];
#pragma unroll
    for (int i = 0; i < 3; i++) {
        int u = i*512 + tid;
        int a = u >> 2, s = u & 3;
        int grp = a / 48, rem = a - grp*48;
        int t = rem >> 4, clo = rem & 15;
        bcol0[i] = grp*64 + t*16 + clo;                  // ks<16: types r,z,gin
        bcol1[i] = grp*64 + ((t==2) ? 48 : t*16) + clo;  // ks>=16: r,z,ghn
        bsrc[i] = (s ^ ((a >> 2) & 3)) * 8;
        bdst[i] = u * 8;
    }

    auto STAGE = [&](int kst) {
        int b = kst % 3;
        GLOAD_LDS16(A + (size_t)(n0 + arow)*640 + kst*32 + asrc, sm.As[b] + adst);
        const unsigned short* WBk = WBl + kst*32;
        bool p1 = kst < 16;
#pragma unroll
        for (int i = 0; i < 3; i++) {
            int cp = p1 ? bcol0[i] : bcol1[i];
            GLOAD_LDS16(WBk + (size_t)cp*640 + bsrc[i], sm.u.Bs[b] + bdst[i]);
        }
    };

    f32x4 acc[8][4] = {};

    STAGE(0); STAGE(1);
    asm volatile("s_waitcnt vmcnt(4)\n\ts_barrier" ::: "memory");
    for (int ks = 0; ks < 16; ks++) {
        STAGE(ks + 2);
        CSTEP(ks % 3, 2);
        asm volatile("s_waitcnt vmcnt(4)\n\ts_barrier" ::: "memory");
    }
    for (int ks = 16; ks < 20; ks++) {
        if (ks < 18) STAGE(ks + 2);
        CSTEP(ks % 3, 3);
        if (ks < 18)
            asm volatile("s_waitcnt vmcnt(4)\n\ts_barrier" ::: "memory");
        else if (ks == 18)
            asm volatile("s_waitcnt vmcnt(0)\n\ts_barrier" ::: "memory");
    }
    __syncthreads();   // all Bs reads done block-wide; hnewB may now alias

    // ---- GRU in registers: lane owns channel chn x 32 rows ----
    {
        const int chn = wid*16 + l15;
        float c3r = c34l[chn],     c3z = c34l[128+chn], c3n = c34l[256+chn];
        float c4r = c34l[384+chn], c4z = c34l[512+chn], c4n = c34l[640+chn];
        float br   = bihl[chn]     + bhhl[chn];
        float bz   = bihl[128+chn] + bhhl[128+chn];
        float bin_ = bihl[256+chn];
        float bhn_ = bhhl[256+chn];
#pragma unroll
        for (int mi = 0; mi < 8; mi++) {
#pragma unroll
            for (int q = 0; q < 4; q++) {
                int row = mi*16 + l4*4 + q;
                size_t v = (size_t)n0 + row;
                float di = indeg[v], dof = outdeg[v];
                float hold = bf2f(A[v*640 + 512 + chn]);
                float rr = sigm(acc[mi][0][q] + di*c3r + dof*c4r + br);
                float zz = sigm(acc[mi][1][q] + di*c3z + dof*c4z + bz);
                float nn = tanh_f(acc[mi][2][q] + di*c3n + dof*c4n + bin_
                                  + rr*(acc[mi][3][q] + bhn_));
                float hv = nn + zz*(hold - nn);
                *(unsigned short*)((char*)sm.u.hnewB + h_addr(row, chn)) = f2bf(hv);
                if (FINAL) hf[v*128 + chn] = hv;
            }
        }
    }
    __syncthreads();   // hnewB visible

    if (!FINAL) {
        // ---- CSR build from pack (counting sort) ----
        if (tid < 16) {
            int gl = tid >> 1, dir = tid & 1;
            const unsigned char* pk = pack + (size_t)(g0 + gl)*32;
            unsigned char* C = sm.csr[gl][dir];
            for (int d = 0; d < 17; d++) C[d] = 0;
            for (int e = 0; e < 32; e++) {
                int p = pk[e];
                int key = dir ? (p & 15) : (p >> 4);
                C[key + 1]++;
            }
            for (int d = 0; d < 16; d++) { C[d+1] += C[d]; sm.offj[gl][dir][d] = C[d]; }
            for (int e = 0; e < 32; e++) {
                int p = pk[e];
                int key = dir ? (p & 15) : (p >> 4);
                int val = dir ? (p >> 4) : (p & 15);
                sm.adj[gl][dir][sm.offj[gl][dir][key]++] = val;
            }
        }
        __syncthreads();
        // ---- gather + coalesced A rewrite (own rows only) ----
        int c = tid & 127, gq = tid >> 7;
#pragma unroll
        for (int gi2 = 0; gi2 < 2; gi2++) {
            int gl = gq + gi2*4, rb = gl*16;
            for (int d = 0; d < 16; d++) {
                float a = 0.f;
                int e0 = sm.csr[gl][0][d], e1 = sm.csr[gl][0][d+1];
                for (int j = e0; j < e1; j++)
                    a += bf2f(*(const unsigned short*)((const char*)sm.u.hnewB
                            + h_addr(rb + sm.adj[gl][0][j], c)));
                float b = 0.f;
                int f0 = sm.csr[gl][1][d], f1 = sm.csr[gl][1][d+1];
                for (int j = f0; j < f1; j++)
                    b += bf2f(*(const unsigned short*)((const char*)sm.u.hnewB
                            + h_addr(rb + sm.adj[gl][1][j], c)));
                int row = rb + d;
                size_t v = (size_t)n0 + row;
                float hv = bf2f(*(const unsigned short*)((const char*)sm.u.hnewB
                            + h_addr(row, c)));
                float di  = (float)(e1 - e0);
                float dof = (float)(f1 - f0);
                A[v*640 + c]       = f2bf(a);
                A[v*640 + 128 + c] = f2bf(b);
                A[v*640 + 256 + c] = f2bf(di  * hv);
                A[v*640 + 384 + c] = f2bf(dof * hv);
                A[v*640 + 512 + c] = f2bf(hv);
            }
        }
    } else {
        // ---- fused gated pooling ----
        if (tid < 128) {
            int row = tid;
            float a1 = 0.f, a2 = 0.f;
            for (int s = 0; s < 16; s++) {
                bf16x8 hv8 = *(const bf16x8*)((const char*)sm.u.hnewB
                              + row*256 + ((s ^ (row & 7)) << 4));
#pragma unroll
                for (int j = 0; j < 8; j++) {
                    float x = bf2f((unsigned short)hv8[j]);
                    int c = s*8 + j;
                    a1 = fmaf(gmW[c],  x, a1);
                    a2 = fmaf(gmiW[c], x, a2);
                }
            }
            sm.gates[0][row] = sigm(a1 + gmb[0]);
            sm.gates[1][row] = sigm(a2 + gmib[0]);
        }
        __syncthreads();
        int c = tid & 127, gq = tid >> 7;
#pragma unroll
        for (int gi2 = 0; gi2 < 2; gi2++) {
            int gl = gq + gi2*4, rb = gl*16;
            float p1 = 0.f, p2 = 0.f;
            for (int r = 0; r < 16; r++) {
                float x = bf2f(*(const unsigned short*)((const char*)sm.u.hnewB
                               + h_addr(rb + r, c)));
                p1 = fmaf(sm.gates[0][rb + r], x, p1);
                p2 = fmaf(sm.gates[1][rb + r], x, p2);
            }
            size_t g = g0 + gl;
            P1[g*128 + c] = p1;
            P2[g*128 + c] = p2;
        }
        if (tid < 16) {
            int gl = tid >> 1, w = tid & 1;
            float s = 0.f;
            for (int r = 0; r < 16; r++) s += sm.gates[w][gl*16 + r];
            sg[(size_t)(g0 + gl)*2 + w] = s;
        }
    }
}

// ---------------------------------------------------------------------------
// Out projection: out[g][c] = fm_W[c].P[g] + fm_b[c]*sg[g].
// ---------------------------------------------------------------------------
__global__ __launch_bounds__(256) void outgemm_kernel(
    const float* __restrict__ P1, const float* __restrict__ P2,
    const float* __restrict__ sg,
    const float* __restrict__ fm_W,  const float* __restrict__ fm_b,
    const float* __restrict__ fmi_W, const float* __restrict__ fmi_b,
    float* __restrict__ out1, float* __restrict__ out2)
{
    const int g0 = blockIdx.x * 32;
    const int t  = threadIdx.x;
    __shared__ float Ws[128][33];
    __shared__ float Ps[32][33];
    const int tc = t & 15, tg = t >> 4;

    for (int pass = 0; pass < 2; pass++) {
        const float* P  = pass ? P2 : P1;
        const float* W  = pass ? fmi_W : fm_W;
        const float* bb = pass ? fmi_b : fm_b;
        float acc[2][8] = {};
        for (int kc = 0; kc < 128; kc += 32) {
#pragma unroll
            for (int i = 0; i < 16; i++) {
                int u = i*256 + t; int r = u >> 5, k = u & 31;
                Ws[r][k] = W[(size_t)r*128 + kc + k];
            }
#pragma unroll
            for (int i = 0; i < 4; i++) {
                int u = i*256 + t; int r = u >> 5, k = u & 31;
                Ps[r][k] = P[(size_t)(g0 + r)*128 + kc + k];
            }
            __syncthreads();
#pragma unroll 8
            for (int k = 0; k < 32; k++) {
                float p0 = Ps[tg*2][k], p1v = Ps[tg*2+1][k];
#pragma unroll
                for (int j = 0; j < 8; j++) {
                    float w = Ws[tc*8+j][k];
                    acc[0][j] = fmaf(p0,  w, acc[0][j]);
                    acc[1][j] = fmaf(p1v, w, acc[1][j]);
                }
            }
            __syncthreads();
        }
        float* outp = pass ? out2 : out1;
#pragma unroll
        for (int i = 0; i < 2; i++) {
            int g = g0 + tg*2 + i;
            float sgv = sg[g*2 + pass];
#pragma unroll
            for (int j = 0; j < 8; j++) {
                int cc = tc*8 + j;
                outp[(size_t)g*128 + cc] = acc[i][j] + bb[cc]*sgv;
            }
        }
    }
}

// ---------------------------------------------------------------------------
extern "C" void kernel_launch(void* const* d_in, const int* in_sizes, int n_in,
                              void* d_out, int out_size, void* d_ws, size_t ws_size,
                              hipStream_t stream)
{
    const float* h     = (const float*)d_in[0];
    const int*   ei    = (const int*)d_in[1];
    const float* msgW  = (const float*)d_in[2];
    const float* msgb  = (const float*)d_in[3];
    const float* msgrW = (const float*)d_in[4];
    const float* msgrb = (const float*)d_in[5];
    const float* Wih   = (const float*)d_in[6];
    const float* Whh   = (const float*)d_in[7];
    const float* bih   = (const float*)d_in[8];
    const float* bhh   = (const float*)d_in[9];
    const float* fmW   = (const float*)d_in[10];
    const float* fmb   = (const float*)d_in[11];
    const float* gmW   = (const float*)d_in[12];
    const float* gmb   = (const float*)d_in[13];
    const float* fmiW  = (const float*)d_in[14];
    const float* fmib  = (const float*)d_in[15];
    const float* gmiW  = (const float*)d_in[16];
    const float* gmib  = (const float*)d_in[17];

    char* w = (char*)d_ws;
    unsigned short* A    = (unsigned short*)w;  w += (size_t)NN*640*2;     // 167.8 MB
    unsigned short* WB   = (unsigned short*)w;  w += (size_t)2*512*640*2;  // 1.31 MB
    float* c34   = (float*)w;                   w += (size_t)2*768*4;
    float* indeg = (float*)w;                   w += (size_t)NN*4;
    float* outdeg= (float*)w;                   w += (size_t)NN*4;
    unsigned char* pack = (unsigned char*)w;    w += (size_t)B_GRAPHS*32;
    float* P1    = (float*)w;                   w += (size_t)B_GRAPHS*128*4;
    float* P2    = (float*)w;                   w += (size_t)B_GRAPHS*128*4;
    float* sgb   = (float*)w;                   w += (size_t)B_GRAPHS*2*4;

    float* hf   = (float*)d_out;
    float* out1 = hf + (size_t)NN*128;
    float* out2 = out1 + (size_t)B_GRAPHS*128;

    int compose_items = 2*512*640 + 2*2*384;
    compose_kernel<<<(compose_items + 255)/256, 256, 0, stream>>>(
        msgW, msgrW, Wih, Whh, msgb, msgrb, WB, c34);

    init_kernel<<<B_GRAPHS, 128, 0, stream>>>(h, ei, A, indeg, outdeg, pack);

    fused_kernel<false><<<NN/128, 512, 0, stream>>>(
        A, WB, indeg, outdeg, pack, c34, bih, bhh,
        gmW, gmb, gmiW, gmib, nullptr, nullptr, nullptr, nullptr);
    fused_kernel<true><<<NN/128, 512, 0, stream>>>(
        A, WB + (size_t)512*640, indeg, outdeg, pack,
        c34 + 768, bih + 384, bhh + 384,
        gmW, gmb, gmiW, gmib, hf, P1, P2, sgb);

    outgemm_kernel<<<B_GRAPHS/32, 256, 0, stream>>>(
        P1, P2, sgb, fmW, fmb, fmiW, fmib, out1, out2);
}